// Round 1
// baseline (250.080 us; speedup 1.0000x reference)
//
#include <hip/hip_runtime.h>
#include <math.h>

// SelfAttentionLayer B=4, N=2048, D=E=1024, fp32 in/out.
// out[b,j,e] = sum_i softmax_i(q_i . k_j / 32) * v[b,i,e]
// R10: port gemm_qkv + gemm_scores to the 256x256 8-phase schedule
//      (T2 swizzle + T3/T4 counted vmcnt + T5 setprio). K-split half-tiles
//      [256x32] give 2-phase read windows -> race-free stage schedule with
//      vmcnt(4) at phases 4/8 only (never 0 in main loop). gemm_pv kept at
//      128x128 (256^2 would halve CU coverage at its 128-block grid).
//
// ws (ushort): xb[8M] Wqkvt[3M] QKb[16M] Vtb[8M] Pb[16M] l[8192 f32].

typedef __bf16 bf16x8 __attribute__((ext_vector_type(8)));
typedef float f32x4 __attribute__((ext_vector_type(4)));

static __device__ __forceinline__ unsigned short f2bf(float f) {
    unsigned u = __float_as_uint(f);
    u += 0x7fff + ((u >> 16) & 1);   // round-to-nearest-even
    return (unsigned short)(u >> 16);
}

#define GLDS16(gptr, lptr)                                                            \
    __builtin_amdgcn_global_load_lds(                                                 \
        (const __attribute__((address_space(1))) void*)(gptr),                        \
        (__attribute__((address_space(3))) void*)(lptr), 16, 0, 0)

// ===================== 256x256 8-phase GEMM core =====================
// A,B row-major [rows x ld], both K-major (B is N x K, i.e. B^T layout).
// K = 1024 fixed (16 K-tiles of 64, 8 iterations of 2 tiles).
// 512 threads = 8 waves (2 M x 4 N); per-wave output 128x64.
// LDS 128 KiB: [buf:2][op A=0/B=+16384][khalf:2][256 rows x 32 cols].
// Stage: per half-tile each thread issues 2 global_load_lds_dwordx4.
// Region read windows (phases, per iteration; buf0 = even tile, buf1 = odd):
//   A-K0(0):1-2  B-K0(0):1  A-K1(0):3-4  B-K1(0):3
//   A-K0(1):5-6  B-K0(1):5  A-K1(1):7-8  B-K1(1):7
// Stage schedule (tile t1=2i+1, t2=2i+2, t3=2i+3):
//   ph1:A-K1(t1) ph2:B-K1(t1) ph3:A-K0(t2) ph4:B-K0(t2)
//   ph5:A-K1(t2) ph6:B-K1(t2) ph7:A-K0(t3) ph8:B-K0(t3)
// Every stage lands one closing-barrier after its region's last reader.
// vmcnt(4) at ph4 covers reads of ph5..ph8+2; vmcnt(4) at ph8 covers ph1..ph4.
__device__ __forceinline__ void gemm256_core(
    const unsigned short* __restrict__ Ab,   // + gm0*ld
    const unsigned short* __restrict__ Bb,   // + gn0*ld
    const long ld, unsigned short* lds, f32x4 acc[8][4])
{
    const int tid  = threadIdx.x;
    const int w    = tid >> 6;
    const int lane = tid & 63;

    // staging addressing: lane -> (row sub 0..15, col group 0..3)
    const int  rsub  = lane >> 2;
    const int  sgrp  = lane & 3;
    const int  colsw = ((sgrp ^ (rsub & 3)) * 8);     // source-side swizzle
    const long rowoff = (long)(w * 16 + rsub);

    const unsigned short* apg = Ab + rowoff * ld + colsw;
    const unsigned short* bpg = Bb + rowoff * ld + colsw;

    unsigned short* dA = lds + w * 512;
    unsigned short* dB = lds + 16384 + w * 512;

    // fragment addressing
    const int fr   = lane & 15;
    const int quad = lane >> 4;
    const int wm   = (w >> 2) * 128;
    const int wn   = (w & 3) * 64;
    const int aoff = (wm + fr) * 32 + ((quad ^ (fr & 3)) * 8);  // read-side swizzle
    const int boff = (wn + fr) * 32 + ((quad ^ (fr & 3)) * 8);

#define STG_A(kt, kh, buf) do {                                             \
    const unsigned short* g_ = apg + (long)(kt) * 64 + (kh) * 32;           \
    unsigned short* d_ = dA + (buf) * 32768 + (kh) * 8192;                  \
    GLDS16(g_, d_); GLDS16(g_ + 128 * ld, d_ + 4096); } while (0)
#define STG_B(kt, kh, buf) do {                                             \
    const unsigned short* g_ = bpg + (long)(kt) * 64 + (kh) * 32;           \
    unsigned short* d_ = dB + (buf) * 32768 + (kh) * 8192;                  \
    GLDS16(g_, d_); GLDS16(g_ + 128 * ld, d_ + 4096); } while (0)

    bf16x8 af[4], bf[4];
#define LOADB(buf, ks) do {                                                 \
    const unsigned short* p_ = lds + 16384 + (buf) * 32768 + (ks) * 8192 + boff; \
    bf[0] = *(const bf16x8*)(p_);        bf[1] = *(const bf16x8*)(p_ + 512);     \
    bf[2] = *(const bf16x8*)(p_ + 1024); bf[3] = *(const bf16x8*)(p_ + 1536); } while (0)
#define LOADA(buf, ks, mh) do {                                             \
    const unsigned short* p_ = lds + (buf) * 32768 + (ks) * 8192 + (mh) * 2048 + aoff; \
    af[0] = *(const bf16x8*)(p_);        af[1] = *(const bf16x8*)(p_ + 512);     \
    af[2] = *(const bf16x8*)(p_ + 1024); af[3] = *(const bf16x8*)(p_ + 1536); } while (0)

#define MFMA16(mh) do {                                                     \
    __builtin_amdgcn_s_setprio(1);                                          \
    _Pragma("unroll") for (int m_ = 0; m_ < 4; m_++)                        \
    _Pragma("unroll") for (int n_ = 0; n_ < 4; n_++)                        \
        acc[(mh) * 4 + m_][n_] = __builtin_amdgcn_mfma_f32_16x16x32_bf16(   \
            af[m_], bf[n_], acc[(mh) * 4 + m_][n_], 0, 0, 0);               \
    __builtin_amdgcn_s_setprio(0); } while (0)

#define BARSYNC  __builtin_amdgcn_s_barrier()
#define WAITLGKM do { asm volatile("s_waitcnt lgkmcnt(0)" ::: "memory");    \
                      __builtin_amdgcn_sched_barrier(0); } while (0)
#define WAITV4   asm volatile("s_waitcnt vmcnt(4)" ::: "memory")

#pragma unroll
    for (int i = 0; i < 8; i++)
#pragma unroll
        for (int j = 0; j < 4; j++) acc[i][j] = f32x4{0.f, 0.f, 0.f, 0.f};

    // prologue: tile0 (all 4 halves) -> buf0; tile1 (K0 halves) -> buf1
    STG_A(0, 0, 0); STG_B(0, 0, 0); STG_A(0, 1, 0); STG_B(0, 1, 0);
    STG_A(1, 0, 1); STG_B(1, 0, 1);
    asm volatile("s_waitcnt vmcnt(4)" ::: "memory");   // tile0 landed
    BARSYNC;

#pragma unroll 1
    for (int i = 0; i < 8; ++i) {
        const int t1 = 2 * i + 1;
        const int t2 = (2 * i + 2) & 15;   // wraps harmlessly on last iter
        const int t3 = (2 * i + 3) & 15;
        // ph1: tile 2i, K-slice 0, M-half 0
        LOADB(0, 0); LOADA(0, 0, 0); STG_A(t1, 1, 1);
        BARSYNC; WAITLGKM; MFMA16(0); BARSYNC;
        // ph2: K0, M-half 1 (bf reused)
        LOADA(0, 0, 1); STG_B(t1, 1, 1);
        BARSYNC; WAITLGKM; MFMA16(1); BARSYNC;
        // ph3: K1, M-half 0
        LOADB(0, 1); LOADA(0, 1, 0); STG_A(t2, 0, 0);
        BARSYNC; WAITLGKM; MFMA16(0); BARSYNC;
        // ph4: K1, M-half 1  + counted wait for buf1(K0)
        LOADA(0, 1, 1); STG_B(t2, 0, 0);
        BARSYNC; WAITLGKM; MFMA16(1); WAITV4; BARSYNC;
        // ph5: tile 2i+1, K0, M-half 0
        LOADB(1, 0); LOADA(1, 0, 0); STG_A(t2, 1, 0);
        BARSYNC; WAITLGKM; MFMA16(0); BARSYNC;
        // ph6
        LOADA(1, 0, 1); STG_B(t2, 1, 0);
        BARSYNC; WAITLGKM; MFMA16(1); BARSYNC;
        // ph7
        LOADB(1, 1); LOADA(1, 1, 0); STG_A(t3, 0, 1);
        BARSYNC; WAITLGKM; MFMA16(0); BARSYNC;
        // ph8  + counted wait for next buf0
        LOADA(1, 1, 1); STG_B(t3, 0, 1);
        BARSYNC; WAITLGKM; MFMA16(1); WAITV4; BARSYNC;
    }
    asm volatile("s_waitcnt vmcnt(0)" ::: "memory");   // drain dummy stages

#undef STG_A
#undef STG_B
#undef LOADB
#undef LOADA
#undef MFMA16
#undef BARSYNC
#undef WAITLGKM
#undef WAITV4
}

// ---------------- QKV fused GEMM (256^2 8-phase) ----------------
// A = xb [8192x1024]; B = Wqkvt [3072x1024] (Wq^T|Wk^T|Wv^T).
// n < 2048 -> QK[m*2048 + n] (bf16); n >= 2048 -> Vt[(n-2048)*8192 + m]
__global__ __launch_bounds__(512, 2) void gemm_qkv256(
    const unsigned short* __restrict__ A, const unsigned short* __restrict__ B,
    unsigned short* __restrict__ QK, unsigned short* __restrict__ Vt)
{
    __shared__ unsigned short lds[65536];
    const long gm0 = (long)blockIdx.y * 256;
    const long gn0 = (long)blockIdx.x * 256;

    f32x4 acc[8][4];
    gemm256_core(A + gm0 * 1024, B + gn0 * 1024, 1024, lds, acc);

    const int tid = threadIdx.x;
    const int w = tid >> 6, lane = tid & 63;
    const int fr = lane & 15, quad = lane >> 4;
    const int wm = (w >> 2) * 128, wn = (w & 3) * 64;

    if (gn0 < 2048) {
#pragma unroll
        for (int mi = 0; mi < 8; mi++) {
            const long rb = gm0 + wm + (mi >> 2) * 64 + (mi & 3) * 16 + quad * 4;
#pragma unroll
            for (int n = 0; n < 4; n++) {
                const long cb = gn0 + wn + n * 16 + fr;
#pragma unroll
                for (int rr = 0; rr < 4; rr++)
                    QK[(rb + rr) * 2048L + cb] = f2bf(acc[mi][n][rr]);
            }
        }
    } else {
#pragma unroll
        for (int mi = 0; mi < 8; mi++) {
            const long rb = gm0 + wm + (mi >> 2) * 64 + (mi & 3) * 16 + quad * 4;
#pragma unroll
            for (int n = 0; n < 4; n++) {
                const long ce = gn0 - 2048 + wn + n * 16 + fr;
                ushort4 o;
                o.x = f2bf(acc[mi][n][0]);
                o.y = f2bf(acc[mi][n][1]);
                o.z = f2bf(acc[mi][n][2]);
                o.w = f2bf(acc[mi][n][3]);
                *(ushort4*)&Vt[ce * 8192L + rb] = o;
            }
        }
    }
}

// ------------- scores GEMM (256^2 8-phase): P'[j,i] = exp((K_j.Q_i)/32) -----
__global__ __launch_bounds__(512, 2) void gemm_scores256(
    const unsigned short* __restrict__ QKb, unsigned short* __restrict__ P,
    float* __restrict__ l)
{
    __shared__ unsigned short lds[65536];
    const int bz = blockIdx.z;
    const long gm0 = (long)blockIdx.y * 256;   // j (K rows)
    const long gn0 = (long)blockIdx.x * 256;   // i (Q rows)

    const unsigned short* Ab = QKb + (long)bz * 2048 * 2048 + 1024 + gm0 * 2048;
    const unsigned short* Bb = QKb + (long)bz * 2048 * 2048 + gn0 * 2048;

    f32x4 acc[8][4];
    gemm256_core(Ab, Bb, 2048, lds, acc);

    const int tid = threadIdx.x;
    const int w = tid >> 6, lane = tid & 63;
    const int fr = lane & 15, quad = lane >> 4;
    const int wm = (w >> 2) * 128, wn = (w & 3) * 64;

    unsigned short* Pb = P + (long)bz * 2048 * 2048;
    float* lb = l + (long)bz * 2048;
    const float scale = 1.0f / 32.0f;
#pragma unroll
    for (int mi = 0; mi < 8; mi++) {
        const long rb = gm0 + wm + (mi >> 2) * 64 + (mi & 3) * 16 + quad * 4;
        float rs[4] = {0.f, 0.f, 0.f, 0.f};
#pragma unroll
        for (int n = 0; n < 4; n++) {
            const long cb = gn0 + wn + n * 16 + fr;
#pragma unroll
            for (int rr = 0; rr < 4; rr++) {
                float e = __expf(acc[mi][n][rr] * scale);
                rs[rr] += e;
                Pb[(rb + rr) * 2048L + cb] = f2bf(e);
            }
        }
#pragma unroll
        for (int rr = 0; rr < 4; rr++) {
#pragma unroll
            for (int m = 8; m > 0; m >>= 1) rs[rr] += __shfl_xor(rs[rr], m, 16);
        }
        if (fr == 0) {
#pragma unroll
            for (int rr = 0; rr < 4; rr++)
                atomicAdd(&lb[rb + rr], rs[rr]);
        }
    }
}

// ---------------- PV GEMM: 128x128 tiles, fp32 out, /l[row] ----------------
// out_b[j,e] = (sum_i P'_b[j,i] * Vt[e, b*2048+i]) / l[b][j]
// grid (8 e-tiles, 16 j-tiles, 4 batches). Same-e blocks are 8 apart in
// dispatch order -> same XCD -> Vt tile stays L2-resident.
__global__ __launch_bounds__(256) void gemm_pv(
    const unsigned short* __restrict__ P, const unsigned short* __restrict__ Vt,
    const float* __restrict__ l, float* __restrict__ out)
{
    __shared__ unsigned short As[128 * 64];
    __shared__ unsigned short Bs[128 * 64];

    const int tid  = threadIdx.x;
    const int wave = tid >> 6;
    const int lane = tid & 63;
    const int bz   = blockIdx.z;
    const long gm0 = (long)blockIdx.y * 128;   // j
    const long gn0 = (long)blockIdx.x * 128;   // e

    const unsigned short* Ab = P + (long)bz * 2048 * 2048;
    const unsigned short* Bb = Vt + (long)bz * 2048;

    const int r = lane >> 3;
    const int s = lane & 7;
    const int cg = (s ^ r) * 8;
    const unsigned short* ap = Ab + (gm0 + wave * 32 + r) * 2048L + cg;
    const unsigned short* bp = Bb + (gn0 + wave * 32 + r) * 8192L + cg;
    unsigned short* asl = &As[wave * 2048];
    unsigned short* bsl = &Bs[wave * 2048];

    const int wm   = (wave & 1) * 64;
    const int wn   = (wave >> 1) * 64;
    const int fr   = lane & 15;
    const int quad = lane >> 4;
    const int sw   = fr & 7;

    f32x4 acc[4][4];
#pragma unroll
    for (int i = 0; i < 4; i++)
#pragma unroll
        for (int j = 0; j < 4; j++) acc[i][j] = f32x4{0.f, 0.f, 0.f, 0.f};

    for (int k0 = 0; k0 < 2048; k0 += 64) {
        GLDS16(ap, asl);
        GLDS16(ap + 8 * 2048L, asl + 512);
        GLDS16(ap + 16 * 2048L, asl + 1024);
        GLDS16(ap + 24 * 2048L, asl + 1536);
        GLDS16(bp, bsl);
        GLDS16(bp + 8 * 8192L, bsl + 512);
        GLDS16(bp + 16 * 8192L, bsl + 1024);
        GLDS16(bp + 24 * 8192L, bsl + 1536);
        ap += 64;
        bp += 64;
        __syncthreads();

#pragma unroll
        for (int t = 0; t < 2; t++) {
            const int qs = ((t * 4 + quad) ^ sw) * 8;
            bf16x8 af[4], bf[4];
#pragma unroll
            for (int i = 0; i < 4; i++)
                af[i] = *(const bf16x8*)&As[(wm + i * 16 + fr) * 64 + qs];
#pragma unroll
            for (int j = 0; j < 4; j++)
                bf[j] = *(const bf16x8*)&Bs[(wn + j * 16 + fr) * 64 + qs];
#pragma unroll
            for (int i = 0; i < 4; i++)
#pragma unroll
                for (int j = 0; j < 4; j++)
                    acc[i][j] = __builtin_amdgcn_mfma_f32_16x16x32_bf16(
                        af[i], bf[j], acc[i][j], 0, 0, 0);
        }
        __syncthreads();
    }

    float* Ob = out + (long)bz * 2048 * 1024;
    const float* lb = l + (long)bz * 2048;
    const long crow0 = gm0 + wm + quad * 4;
#pragma unroll
    for (int i = 0; i < 4; i++) {
        const long rb = crow0 + i * 16;
        float inv[4];
#pragma unroll
        for (int rr = 0; rr < 4; rr++) inv[rr] = 1.0f / lb[rb + rr];
#pragma unroll
        for (int j = 0; j < 4; j++) {
            const long cb = gn0 + wn + j * 16 + fr;
#pragma unroll
            for (int rr = 0; rr < 4; rr++)
                Ob[(rb + rr) * 1024L + cb] = acc[i][j][rr] * inv[rr];
        }
    }
}

// Fused prep: [0,8192) convert x; [8192,8192+3072) transpose weights;
// block 11264 zeroes l (8192 floats).
__global__ __launch_bounds__(256) void prep(
    const float* __restrict__ x,
    const float* __restrict__ Wq, const float* __restrict__ Wk,
    const float* __restrict__ Wv,
    unsigned short* __restrict__ xb, unsigned short* __restrict__ Wqkvt,
    float* __restrict__ l)
{
    __shared__ float t[32][33];
    const int b = blockIdx.x;
    const int tid = threadIdx.x;
    if (b < 8192) {
        int i = b * 256 + tid;
        float4 v = ((const float4*)x)[i];
        ushort4 o;
        o.x = f2bf(v.x); o.y = f2bf(v.y); o.z = f2bf(v.z); o.w = f2bf(v.w);
        ((ushort4*)xb)[i] = o;
        return;
    }
    if (b == 8192 + 3072) {
        float4 z = {0.f, 0.f, 0.f, 0.f};
#pragma unroll
        for (int i = 0; i < 8; i++)
            ((float4*)l)[tid * 8 + i] = z;
        return;
    }
    int tix = b - 8192;
    const int w = tix >> 10;
    tix &= 1023;
    const float* W = (w == 0) ? Wq : (w == 1) ? Wk : Wv;
    unsigned short* Wt = Wqkvt + (long)w * 1024 * 1024;
    const int bx = (tix & 31) * 32;
    const int by = (tix >> 5) * 32;
    const int tx = tid & 31;
    const int ty = (tid >> 5) * 4;
#pragma unroll
    for (int j = 0; j < 4; j++)
        t[ty + j][tx] = W[(long)(by + ty + j) * 1024 + bx + tx];
    __syncthreads();
#pragma unroll
    for (int j = 0; j < 4; j++)
        Wt[(long)(bx + ty + j) * 1024 + by + tx] = f2bf(t[tx][ty + j]);
}

extern "C" void kernel_launch(void* const* d_in, const int* in_sizes, int n_in,
                              void* d_out, int out_size, void* d_ws,
                              size_t ws_size, hipStream_t stream)
{
    const float* x  = (const float*)d_in[0];
    const float* Wq = (const float*)d_in[1];
    const float* Wk = (const float*)d_in[2];
    const float* Wv = (const float*)d_in[3];
    float* out = (float*)d_out;

    const long M1 = 1024 * 1024;
    unsigned short* u     = (unsigned short*)d_ws;
    unsigned short* xb    = u;                  // 8M
    unsigned short* Wqkvt = u + 8 * M1;         // 3M
    unsigned short* QKb   = Wqkvt + 3 * M1;     // 16M [8192 x 2048]
    unsigned short* Vtb   = QKb + 16 * M1;      // 8M  [1024 x 8192]
    unsigned short* Pb    = Vtb + 8 * M1;       // 16M [4 x 2048 x 2048]
    float* l              = (float*)(Pb + 16 * M1);  // 8192 f32

    prep<<<dim3(8192 + 3072 + 1), dim3(256), 0, stream>>>(x, Wq, Wk, Wv, xb, Wqkvt, l);

    // QKV fused: [8192x1024] @ [3072x1024]^T, 256^2 8-phase
    gemm_qkv256<<<dim3(12, 32), dim3(512), 0, stream>>>(xb, Wqkvt, QKb, Vtb);

    // P'[j,i] = exp((K_j.Q_i)/32) bf16, + row sums l, 256^2 8-phase
    gemm_scores256<<<dim3(8, 8, 4), dim3(512), 0, stream>>>(QKb, Pb, l);

    // out = (P' @ V) / l  (128x128 tiles)
    gemm_pv<<<dim3(8, 16, 4), dim3(256), 0, stream>>>(Pb, Vtb, l, out);
}

// Round 2
// 236.468 us; speedup vs baseline: 1.0576x; 1.0576x over previous
//
#include <hip/hip_runtime.h>
#include <math.h>

// SelfAttentionLayer B=4, N=2048, D=E=1024, fp32 in/out.
// out[b,j,e] = sum_i softmax_i(q_i . k_j / 32) * v[b,i,e]
// R11: fix R10's 4-way LDS read conflict (32-col rows -> 64-col rows,
//      proven (s^r)/(quad^sw) swizzle, 2-way = free). Phases are now
//      C-quadrants (mh,nh) x K=64 per the m201 template. Stage units match
//      read-sets exactly (A by mh, B by nh interleaved) -> 2-phase read
//      windows -> race-free 1-stage/phase schedule, vmcnt(4) at ph4/ph8
//      only. + bijective XCD swizzle on both 256^2 kernels.
//
// ws (ushort): xb[8M] Wqkvt[3M] QKb[16M] Vtb[8M] Pb[16M] l[8192 f32].

typedef __bf16 bf16x8 __attribute__((ext_vector_type(8)));
typedef float f32x4 __attribute__((ext_vector_type(4)));

static __device__ __forceinline__ unsigned short f2bf(float f) {
    unsigned u = __float_as_uint(f);
    u += 0x7fff + ((u >> 16) & 1);   // round-to-nearest-even
    return (unsigned short)(u >> 16);
}

#define GLDS16(gptr, lptr)                                                            \
    __builtin_amdgcn_global_load_lds(                                                 \
        (const __attribute__((address_space(1))) void*)(gptr),                        \
        (__attribute__((address_space(3))) void*)(lptr), 16, 0, 0)

// ===================== 256x256 8-phase GEMM core =====================
// A,B row-major [rows x ld], both K-major. K = 1024 (16 tiles of 64).
// 512 threads = 8 waves (2M x 4N); per-wave output 128x64.
// LDS 128 KiB ushort map: A[buf][256 rows][64] at buf*16384;
//                         B[buf][256 rows][64] at 32768 + buf*16384.
// Row swizzle: LDS chunk p of row rr holds global 8-col chunk p^(rr&7).
// Phase (buf, mh, nh) = C-quadrant x K=64: 16 MFMA; ds_reads 12/4/8/4.
// Stage units (16KB, 2 GLDS16/thread) match read sets:
//   A-unit(mh): rows {0,128}+mh*64..+63   read exactly at the 2 mh-phases
//   B-unit(nh): rows {0,64,128,192}+nh*32..+31  read at the 2 nh-phases
// Schedule (iter i: buf0=tile 2i, buf1=2i+1; t1=2i+1,t2=2i+2,t3=2i+3):
//  ph1(0,0,0): ldA0+ldB0, STG_B(t1,nh0,b1)   ph5(1,0,0): ldA0+ldB0, STG_A(t2,mh1,b0)
//  ph2(0,0,1): ldB1,      STG_A(t1,mh1,b1)   ph6(1,0,1): ldB1,      STG_B(t2,nh0,b0)
//  ph3(0,1,1): ldA1,      STG_A(t2,mh0,b0)   ph7(1,1,1): ldA1,      STG_A(t3,mh0,b1)
//  ph4(0,1,0): ldB0,      STG_B(t2,nh1,b0)   ph8(1,1,0): ldB0,      STG_B(t3,nh1,b1)
//  WAITV4 after ph4 MFMA (completes buf1<-t1) and after ph8 (buf0<-t2).
// Every stage issues >=1 barrier after its unit's last read; lands >=2
// phases before its first read. Invariant entering ph1: 4 loads in flight.
__device__ __forceinline__ void gemm256_core(
    const unsigned short* __restrict__ Ab,   // + gm0*ld
    const unsigned short* __restrict__ Bb,   // + gn0*ld
    const long ld, unsigned short* lds, f32x4 acc[8][4])
{
    const int tid  = threadIdx.x;
    const int w    = tid >> 6;
    const int lane = tid & 63;

    // staging lane split: r = row 0..7, s = chunk 0..7, source-side swizzle
    const int r  = lane >> 3;
    const int s  = lane & 7;
    const int cg = (s ^ r) * 8;

    // fragment addressing
    const int fr    = lane & 15;
    const int quad  = lane >> 4;
    const int sw    = fr & 7;
    const int arow0 = (w >> 2) * 128;
    const int brow0 = (w & 3) * 64;

#define STG_A(t, mh, buf) do {                                              \
    const int rb_ = (w >> 2) * 128 + (mh) * 64 + (w & 3) * 16;              \
    const unsigned short* g_ = Ab + (long)(rb_ + r) * ld + (long)(t) * 64 + cg; \
    unsigned short* d_ = lds + (buf) * 16384 + rb_ * 64;                    \
    GLDS16(g_, d_); GLDS16(g_ + 8 * ld, d_ + 512); } while (0)
#define STG_B(t, nh, buf) do {                                              \
    const int rb_ = (w >> 1) * 64 + (nh) * 32 + (w & 1) * 16;               \
    const unsigned short* g_ = Bb + (long)(rb_ + r) * ld + (long)(t) * 64 + cg; \
    unsigned short* d_ = lds + 32768 + (buf) * 16384 + rb_ * 64;            \
    GLDS16(g_, d_); GLDS16(g_ + 8 * ld, d_ + 512); } while (0)

    bf16x8 af[4][2], bf[2][2];
#define LOADA(buf, mh) do {                                                 \
    _Pragma("unroll") for (int ks_ = 0; ks_ < 2; ks_++)                     \
    _Pragma("unroll") for (int i_ = 0; i_ < 4; i_++)                        \
        af[i_][ks_] = *(const bf16x8*)&lds[(buf) * 16384 +                  \
            (arow0 + (mh) * 64 + i_ * 16 + fr) * 64 +                       \
            ((ks_ * 4 + quad) ^ sw) * 8]; } while (0)
#define LOADB(buf, nh) do {                                                 \
    _Pragma("unroll") for (int ks_ = 0; ks_ < 2; ks_++)                     \
    _Pragma("unroll") for (int j_ = 0; j_ < 2; j_++)                        \
        bf[j_][ks_] = *(const bf16x8*)&lds[32768 + (buf) * 16384 +          \
            (brow0 + (nh) * 32 + j_ * 16 + fr) * 64 +                       \
            ((ks_ * 4 + quad) ^ sw) * 8]; } while (0)

#define MFMA16(mh, nh) do {                                                 \
    __builtin_amdgcn_s_setprio(1);                                          \
    _Pragma("unroll") for (int ks_ = 0; ks_ < 2; ks_++)                     \
    _Pragma("unroll") for (int i_ = 0; i_ < 4; i_++)                        \
    _Pragma("unroll") for (int j_ = 0; j_ < 2; j_++)                        \
        acc[(mh) * 4 + i_][(nh) * 2 + j_] =                                 \
            __builtin_amdgcn_mfma_f32_16x16x32_bf16(                        \
                af[i_][ks_], bf[j_][ks_],                                   \
                acc[(mh) * 4 + i_][(nh) * 2 + j_], 0, 0, 0);                \
    __builtin_amdgcn_s_setprio(0); } while (0)

#define BARSYNC  __builtin_amdgcn_s_barrier()
#define WAITLGKM do { asm volatile("s_waitcnt lgkmcnt(0)" ::: "memory");    \
                      __builtin_amdgcn_sched_barrier(0); } while (0)
#define WAITV4   asm volatile("s_waitcnt vmcnt(4)" ::: "memory")

#pragma unroll
    for (int i = 0; i < 8; i++)
#pragma unroll
        for (int j = 0; j < 4; j++) acc[i][j] = f32x4{0.f, 0.f, 0.f, 0.f};

    // prologue: buf0 <- tile0 (4 units); buf1 <- tile1 partial (mh0, nh1)
    STG_A(0, 0, 0); STG_A(0, 1, 0); STG_B(0, 0, 0); STG_B(0, 1, 0);
    STG_A(1, 0, 1); STG_B(1, 1, 1);
    asm volatile("s_waitcnt vmcnt(4)" ::: "memory");   // buf0 complete
    BARSYNC;

#pragma unroll 1
    for (int i = 0; i < 8; ++i) {
        const int t1 = 2 * i + 1;
        const int t2 = (2 * i + 2) & 15;   // dummy re-read on last iter (safe)
        const int t3 = (2 * i + 3) & 15;
        // ph1 (buf0, mh0, nh0)
        LOADA(0, 0); LOADB(0, 0); STG_B(t1, 0, 1);
        BARSYNC; WAITLGKM; MFMA16(0, 0); BARSYNC;
        // ph2 (buf0, mh0, nh1)
        LOADB(0, 1); STG_A(t1, 1, 1);
        BARSYNC; WAITLGKM; MFMA16(0, 1); BARSYNC;
        // ph3 (buf0, mh1, nh1)
        LOADA(0, 1); STG_A(t2, 0, 0);
        BARSYNC; WAITLGKM; MFMA16(1, 1); BARSYNC;
        // ph4 (buf0, mh1, nh0) + drain: buf1 <- t1 complete
        LOADB(0, 0); STG_B(t2, 1, 0);
        BARSYNC; WAITLGKM; MFMA16(1, 0); WAITV4; BARSYNC;
        // ph5 (buf1, mh0, nh0)
        LOADA(1, 0); LOADB(1, 0); STG_A(t2, 1, 0);
        BARSYNC; WAITLGKM; MFMA16(0, 0); BARSYNC;
        // ph6 (buf1, mh0, nh1)
        LOADB(1, 1); STG_B(t2, 0, 0);
        BARSYNC; WAITLGKM; MFMA16(0, 1); BARSYNC;
        // ph7 (buf1, mh1, nh1)
        LOADA(1, 1); STG_A(t3, 0, 1);
        BARSYNC; WAITLGKM; MFMA16(1, 1); BARSYNC;
        // ph8 (buf1, mh1, nh0) + drain: buf0 <- t2 complete
        LOADB(1, 0); STG_B(t3, 1, 1);
        BARSYNC; WAITLGKM; MFMA16(1, 0); WAITV4; BARSYNC;
    }
    asm volatile("s_waitcnt vmcnt(0)" ::: "memory");   // drain dummy stages

#undef STG_A
#undef STG_B
#undef LOADA
#undef LOADB
#undef MFMA16
#undef BARSYNC
#undef WAITLGKM
#undef WAITV4
}

// ---------------- QKV fused GEMM (256^2 8-phase) ----------------
// A = xb [8192x1024]; B = Wqkvt [3072x1024] (Wq^T|Wk^T|Wv^T).
// n < 2048 -> QK[m*2048 + n] (bf16); n >= 2048 -> Vt[(n-2048)*8192 + m]
// XCD swizzle: 384 blocks, q=48/XCD -> each XCD owns 4 M-panels x all N.
__global__ __launch_bounds__(512, 2) void gemm_qkv256(
    const unsigned short* __restrict__ A, const unsigned short* __restrict__ B,
    unsigned short* __restrict__ QK, unsigned short* __restrict__ Vt)
{
    __shared__ unsigned short lds[65536];
    const int orig = blockIdx.x;
    const int xcd  = orig & 7;
    const int pos  = orig >> 3;           // 0..47, lid = xcd*48 + pos
    const long gm0 = (long)(xcd * 4 + (pos & 3)) * 256;
    const long gn0 = (long)(pos >> 2) * 256;

    f32x4 acc[8][4];
    gemm256_core(A + gm0 * 1024, B + gn0 * 1024, 1024, lds, acc);

    const int tid = threadIdx.x;
    const int w = tid >> 6, lane = tid & 63;
    const int fr = lane & 15, quad = lane >> 4;
    const int wm = (w >> 2) * 128, wn = (w & 3) * 64;

    if (gn0 < 2048) {
#pragma unroll
        for (int mi = 0; mi < 8; mi++) {
            const long rb = gm0 + wm + (mi >> 2) * 64 + (mi & 3) * 16 + quad * 4;
#pragma unroll
            for (int n = 0; n < 4; n++) {
                const long cb = gn0 + wn + n * 16 + fr;
#pragma unroll
                for (int rr = 0; rr < 4; rr++)
                    QK[(rb + rr) * 2048L + cb] = f2bf(acc[mi][n][rr]);
            }
        }
    } else {
#pragma unroll
        for (int mi = 0; mi < 8; mi++) {
            const long rb = gm0 + wm + (mi >> 2) * 64 + (mi & 3) * 16 + quad * 4;
#pragma unroll
            for (int n = 0; n < 4; n++) {
                const long ce = gn0 - 2048 + wn + n * 16 + fr;
                ushort4 o;
                o.x = f2bf(acc[mi][n][0]);
                o.y = f2bf(acc[mi][n][1]);
                o.z = f2bf(acc[mi][n][2]);
                o.w = f2bf(acc[mi][n][3]);
                *(ushort4*)&Vt[ce * 8192L + rb] = o;
            }
        }
    }
}

// ------------- scores GEMM (256^2 8-phase): P'[j,i] = exp((K_j.Q_i)/32) -----
// 256 blocks = exact single round. XCD swizzle: each XCD owns half a batch.
__global__ __launch_bounds__(512, 2) void gemm_scores256(
    const unsigned short* __restrict__ QKb, unsigned short* __restrict__ P,
    float* __restrict__ l)
{
    __shared__ unsigned short lds[65536];
    const int orig = blockIdx.x;
    const int xcd  = orig & 7;
    const int pos  = orig >> 3;           // 0..31
    const int bz   = xcd >> 1;
    const long gm0 = (long)((xcd & 1) * 4 + (pos >> 3)) * 256;  // j (K rows)
    const long gn0 = (long)(pos & 7) * 256;                     // i (Q rows)

    const unsigned short* Ab = QKb + (long)bz * 2048 * 2048 + 1024 + gm0 * 2048;
    const unsigned short* Bb = QKb + (long)bz * 2048 * 2048 + gn0 * 2048;

    f32x4 acc[8][4];
    gemm256_core(Ab, Bb, 2048, lds, acc);

    const int tid = threadIdx.x;
    const int w = tid >> 6, lane = tid & 63;
    const int fr = lane & 15, quad = lane >> 4;
    const int wm = (w >> 2) * 128, wn = (w & 3) * 64;

    unsigned short* Pb = P + (long)bz * 2048 * 2048;
    float* lb = l + (long)bz * 2048;
    const float scale = 1.0f / 32.0f;
#pragma unroll
    for (int mi = 0; mi < 8; mi++) {
        const long rb = gm0 + wm + (mi >> 2) * 64 + (mi & 3) * 16 + quad * 4;
        float rs[4] = {0.f, 0.f, 0.f, 0.f};
#pragma unroll
        for (int n = 0; n < 4; n++) {
            const long cb = gn0 + wn + n * 16 + fr;
#pragma unroll
            for (int rr = 0; rr < 4; rr++) {
                float e = __expf(acc[mi][n][rr] * scale);
                rs[rr] += e;
                Pb[(rb + rr) * 2048L + cb] = f2bf(e);
            }
        }
#pragma unroll
        for (int rr = 0; rr < 4; rr++) {
#pragma unroll
            for (int m = 8; m > 0; m >>= 1) rs[rr] += __shfl_xor(rs[rr], m, 16);
        }
        if (fr == 0) {
#pragma unroll
            for (int rr = 0; rr < 4; rr++)
                atomicAdd(&lb[rb + rr], rs[rr]);
        }
    }
}

// ---------------- PV GEMM: 128x128 tiles, fp32 out, /l[row] ----------------
// out_b[j,e] = (sum_i P'_b[j,i] * Vt[e, b*2048+i]) / l[b][j]
// grid (8 e-tiles, 16 j-tiles, 4 batches). Same-e blocks are 8 apart in
// dispatch order -> same XCD -> Vt tile stays L2-resident.
__global__ __launch_bounds__(256) void gemm_pv(
    const unsigned short* __restrict__ P, const unsigned short* __restrict__ Vt,
    const float* __restrict__ l, float* __restrict__ out)
{
    __shared__ unsigned short As[128 * 64];
    __shared__ unsigned short Bs[128 * 64];

    const int tid  = threadIdx.x;
    const int wave = tid >> 6;
    const int lane = tid & 63;
    const int bz   = blockIdx.z;
    const long gm0 = (long)blockIdx.y * 128;   // j
    const long gn0 = (long)blockIdx.x * 128;   // e

    const unsigned short* Ab = P + (long)bz * 2048 * 2048;
    const unsigned short* Bb = Vt + (long)bz * 2048;

    const int r = lane >> 3;
    const int s = lane & 7;
    const int cg = (s ^ r) * 8;
    const unsigned short* ap = Ab + (gm0 + wave * 32 + r) * 2048L + cg;
    const unsigned short* bp = Bb + (gn0 + wave * 32 + r) * 8192L + cg;
    unsigned short* asl = &As[wave * 2048];
    unsigned short* bsl = &Bs[wave * 2048];

    const int wm   = (wave & 1) * 64;
    const int wn   = (wave >> 1) * 64;
    const int fr   = lane & 15;
    const int quad = lane >> 4;
    const int sw   = fr & 7;

    f32x4 acc[4][4];
#pragma unroll
    for (int i = 0; i < 4; i++)
#pragma unroll
        for (int j = 0; j < 4; j++) acc[i][j] = f32x4{0.f, 0.f, 0.f, 0.f};

    for (int k0 = 0; k0 < 2048; k0 += 64) {
        GLDS16(ap, asl);
        GLDS16(ap + 8 * 2048L, asl + 512);
        GLDS16(ap + 16 * 2048L, asl + 1024);
        GLDS16(ap + 24 * 2048L, asl + 1536);
        GLDS16(bp, bsl);
        GLDS16(bp + 8 * 8192L, bsl + 512);
        GLDS16(bp + 16 * 8192L, bsl + 1024);
        GLDS16(bp + 24 * 8192L, bsl + 1536);
        ap += 64;
        bp += 64;
        __syncthreads();

#pragma unroll
        for (int t = 0; t < 2; t++) {
            const int qs = ((t * 4 + quad) ^ sw) * 8;
            bf16x8 af[4], bf[4];
#pragma unroll
            for (int i = 0; i < 4; i++)
                af[i] = *(const bf16x8*)&As[(wm + i * 16 + fr) * 64 + qs];
#pragma unroll
            for (int j = 0; j < 4; j++)
                bf[j] = *(const bf16x8*)&Bs[(wn + j * 16 + fr) * 64 + qs];
#pragma unroll
            for (int i = 0; i < 4; i++)
#pragma unroll
                for (int j = 0; j < 4; j++)
                    acc[i][j] = __builtin_amdgcn_mfma_f32_16x16x32_bf16(
                        af[i], bf[j], acc[i][j], 0, 0, 0);
        }
        __syncthreads();
    }

    float* Ob = out + (long)bz * 2048 * 1024;
    const float* lb = l + (long)bz * 2048;
    const long crow0 = gm0 + wm + quad * 4;
#pragma unroll
    for (int i = 0; i < 4; i++) {
        const long rb = crow0 + i * 16;
        float inv[4];
#pragma unroll
        for (int rr = 0; rr < 4; rr++) inv[rr] = 1.0f / lb[rb + rr];
#pragma unroll
        for (int j = 0; j < 4; j++) {
            const long cb = gn0 + wn + j * 16 + fr;
#pragma unroll
            for (int rr = 0; rr < 4; rr++)
                Ob[(rb + rr) * 1024L + cb] = acc[i][j][rr] * inv[rr];
        }
    }
}

// Fused prep: [0,8192) convert x; [8192,8192+3072) transpose weights;
// block 11264 zeroes l (8192 floats).
__global__ __launch_bounds__(256) void prep(
    const float* __restrict__ x,
    const float* __restrict__ Wq, const float* __restrict__ Wk,
    const float* __restrict__ Wv,
    unsigned short* __restrict__ xb, unsigned short* __restrict__ Wqkvt,
    float* __restrict__ l)
{
    __shared__ float t[32][33];
    const int b = blockIdx.x;
    const int tid = threadIdx.x;
    if (b < 8192) {
        int i = b * 256 + tid;
        float4 v = ((const float4*)x)[i];
        ushort4 o;
        o.x = f2bf(v.x); o.y = f2bf(v.y); o.z = f2bf(v.z); o.w = f2bf(v.w);
        ((ushort4*)xb)[i] = o;
        return;
    }
    if (b == 8192 + 3072) {
        float4 z = {0.f, 0.f, 0.f, 0.f};
#pragma unroll
        for (int i = 0; i < 8; i++)
            ((float4*)l)[tid * 8 + i] = z;
        return;
    }
    int tix = b - 8192;
    const int w = tix >> 10;
    tix &= 1023;
    const float* W = (w == 0) ? Wq : (w == 1) ? Wk : Wv;
    unsigned short* Wt = Wqkvt + (long)w * 1024 * 1024;
    const int bx = (tix & 31) * 32;
    const int by = (tix >> 5) * 32;
    const int tx = tid & 31;
    const int ty = (tid >> 5) * 4;
#pragma unroll
    for (int j = 0; j < 4; j++)
        t[ty + j][tx] = W[(long)(by + ty + j) * 1024 + bx + tx];
    __syncthreads();
#pragma unroll
    for (int j = 0; j < 4; j++)
        Wt[(long)(bx + ty + j) * 1024 + by + tx] = f2bf(t[tx][ty + j]);
}

extern "C" void kernel_launch(void* const* d_in, const int* in_sizes, int n_in,
                              void* d_out, int out_size, void* d_ws,
                              size_t ws_size, hipStream_t stream)
{
    const float* x  = (const float*)d_in[0];
    const float* Wq = (const float*)d_in[1];
    const float* Wk = (const float*)d_in[2];
    const float* Wv = (const float*)d_in[3];
    float* out = (float*)d_out;

    const long M1 = 1024 * 1024;
    unsigned short* u     = (unsigned short*)d_ws;
    unsigned short* xb    = u;                  // 8M
    unsigned short* Wqkvt = u + 8 * M1;         // 3M
    unsigned short* QKb   = Wqkvt + 3 * M1;     // 16M [8192 x 2048]
    unsigned short* Vtb   = QKb + 16 * M1;      // 8M  [1024 x 8192]
    unsigned short* Pb    = Vtb + 8 * M1;       // 16M [4 x 2048 x 2048]
    float* l              = (float*)(Pb + 16 * M1);  // 8192 f32

    prep<<<dim3(8192 + 3072 + 1), dim3(256), 0, stream>>>(x, Wq, Wk, Wv, xb, Wqkvt, l);

    // QKV fused: [8192x1024] @ [3072x1024]^T, 256^2 8-phase, XCD-swizzled
    gemm_qkv256<<<dim3(384), dim3(512), 0, stream>>>(xb, Wqkvt, QKb, Vtb);

    // P'[j,i] = exp((K_j.Q_i)/32) bf16, + row sums l, 256^2 8-phase
    gemm_scores256<<<dim3(256), dim3(512), 0, stream>>>(QKb, Pb, l);

    // out = (P' @ V) / l  (128x128 tiles)
    gemm_pv<<<dim3(8, 16, 4), dim3(256), 0, stream>>>(Pb, Vtb, l, out);
}